// Round 1
// 25182.661 us; speedup vs baseline: 1.2377x; 1.2377x over previous
//
#include <hip/hip_runtime.h>

// Problem constants
#define HH    1024
#define DD    256
#define BSB   1024
#define TT    256
#define N3H   3072   // 3*H
#define CAT1  32
#define CAT2E 47

typedef unsigned short u16;
typedef short bf16x8 __attribute__((ext_vector_type(8)));
typedef float f32x4  __attribute__((ext_vector_type(4)));

__device__ __forceinline__ u16 f2bf(float f) {
  // round-to-nearest-even fp32 -> bf16 (finite inputs)
  unsigned int x = __float_as_uint(f);
  unsigned int lsb = (x >> 16) & 1u;
  x += 0x7fffu + lsb;
  return (u16)(x >> 16);
}

// async global->LDS, 16B per lane; LDS dest is wave-uniform base + lane*16
__device__ __forceinline__ void gload_lds16(const u16* src, u16* lds) {
  __builtin_amdgcn_global_load_lds(
      (const __attribute__((address_space(1))) void*)src,
      (__attribute__((address_space(3))) void*)lds, 16, 0, 0);
}

// ---------------------------------------------------------------------------
// GEMM: C[M,N] = A[M,K] @ B[N,K]^T (+bias[col]) (+addend[row,col])
// A,B bf16 (raw u16) row-major; C fp32 with per-arg ldc.
// Block 256 threads = 4 waves; tile 128x128, BK=64.
// Staging: global_load_lds dwordx4, LINEAR LDS [128][64], source pre-swizzled
// by slot^(row&7) so the swizzled ds_read_b128 is bank-conflict-free (rule #21).
// mfma_f32_16x16x32_bf16 layouts (HW-verified m89/m91):
//   A frag: A[m=lane&15][k=(lane>>4)*8+j];  B frag: W[n=lane&15][k=(lane>>4)*8+j]
//   C/D:    col=lane&15, row=(lane>>4)*4+reg
// ---------------------------------------------------------------------------
struct GArg {
  const u16* A; int lda; int K;
  const u16* B; int ldb; int N;   // N = valid output cols (early-exit guard)
  float* C; int ldc;
  const float* bias;    // nullable
  const float* addend;  // nullable, stride ldc
};

#define BM 128
#define BN 128
#define BK 64

__global__ __launch_bounds__(256, 3) void gemm_bt3(GArg ga, GArg gb)
{
  GArg g = (blockIdx.z == 0) ? ga : gb;
  const int colBase = blockIdx.x * BN;
  if (colBase >= g.N) return;                 // head blocks beyond N=256 exit
  const int rowBase = blockIdx.y * BM;

  __shared__ __align__(16) u16 As[BM * BK];   // 16 KiB, linear [row][64]
  __shared__ __align__(16) u16 Bs[BN * BK];   // 16 KiB

  const int tid  = threadIdx.x;
  const int wave = tid >> 6;
  const int lane = tid & 63;
  const int q    = lane >> 4;
  const int l16  = lane & 15;
  const int waveRow = (wave >> 1) * 64;
  const int waveCol = (wave & 1) * 64;

  // staging geometry: each call covers 8 rows x 64B-half? no: lane l writes
  // LDS byte (i*4096 + wave*1024 + l*16) -> row = i*32 + wave*8 + (l>>3),
  // slot = l&7. Pre-swizzle source k-chunk by slot^(row&7) = (l&7)^(l>>3).
  const int  srow = wave * 8 + (lane >> 3);
  const int  sswz = ((lane & 7) ^ (lane >> 3)) << 3;   // k-elem offset (x8)
  const u16* aptr = g.A + (size_t)(rowBase + srow) * g.lda + sswz;
  const u16* bptr = g.B + (size_t)(colBase + srow) * g.ldb + sswz;
  const size_t astep = (size_t)32 * g.lda;
  const size_t bstep = (size_t)32 * g.ldb;
  u16* aldst = &As[wave << 9];   // wave-uniform, +i*2048 elems per iter
  u16* bldst = &Bs[wave << 9];

  f32x4 acc[4][4];
  #pragma unroll
  for (int i = 0; i < 4; ++i)
    #pragma unroll
    for (int j = 0; j < 4; ++j)
      acc[i][j] = (f32x4){0.f, 0.f, 0.f, 0.f};

  for (int k0 = 0; k0 < g.K; k0 += BK) {
    __syncthreads();   // previous iter's ds_reads done before overwrite
    #pragma unroll
    for (int i = 0; i < 4; ++i) {
      gload_lds16(aptr + k0 + (size_t)i * astep, aldst + (i << 11));
      gload_lds16(bptr + k0 + (size_t)i * bstep, bldst + (i << 11));
    }
    __syncthreads();   // compiler drains vmcnt before barrier

    #pragma unroll
    for (int ks = 0; ks < 2; ++ks) {
      bf16x8 af[4], bfr[4];
      const int kb = (ks << 2) + q;            // 16B slot of wanted k-chunk
      #pragma unroll
      for (int mi = 0; mi < 4; ++mi) {
        int r = waveRow + mi * 16 + l16;
        af[mi] = *(const bf16x8*)&As[(r << 6) + ((kb ^ (l16 & 7)) << 3)];
      }
      #pragma unroll
      for (int ni = 0; ni < 4; ++ni) {
        int r = waveCol + ni * 16 + l16;
        bfr[ni] = *(const bf16x8*)&Bs[(r << 6) + ((kb ^ (l16 & 7)) << 3)];
      }
      #pragma unroll
      for (int mi = 0; mi < 4; ++mi)
        #pragma unroll
        for (int ni = 0; ni < 4; ++ni)
          acc[mi][ni] = __builtin_amdgcn_mfma_f32_16x16x32_bf16(af[mi], bfr[ni], acc[mi][ni], 0, 0, 0);
    }
  }

  #pragma unroll
  for (int mi = 0; mi < 4; ++mi) {
    #pragma unroll
    for (int ni = 0; ni < 4; ++ni) {
      #pragma unroll
      for (int r = 0; r < 4; ++r) {
        int row = rowBase + waveRow + mi * 16 + q * 4 + r;
        int col = colBase + waveCol + ni * 16 + l16;
        float v = acc[mi][ni][r];
        if (g.bias)   v += g.bias[col];
        if (g.addend) v += g.addend[(size_t)row * g.ldc + col];
        g.C[(size_t)row * g.ldc + col] = v;
      }
    }
  }
}

// ---------------------------------------------------------------------------
// GRU gate nonlinearity, float4-vectorized: hn = (1-z)*n + z*h
// ---------------------------------------------------------------------------
__device__ __forceinline__ float gate1f(float gir, float ghr, float giz, float ghz,
                                        float gin, float ghn, float hv) {
  float r = 1.f / (1.f + expf(-(gir + ghr)));
  float z = 1.f / (1.f + expf(-(giz + ghz)));
  float n = tanhf(gin + r * ghn);
  return (1.f - z) * n + z * hv;
}

__global__ void gate_kernel(const float4* __restrict__ GI, const float4* __restrict__ GH,
                            float4* __restrict__ h, ushort4* __restrict__ hbf)
{
  int idx = blockIdx.x * blockDim.x + threadIdx.x;   // BS*H/4 = 256K
  int b = idx >> 8, m = idx & 255;                   // m in float4 units (H/4=256)
  size_t base = (size_t)b * 768;                     // 3H/4
  float4 gir = GI[base + m], giz = GI[base + 256 + m], gin = GI[base + 512 + m];
  float4 ghr = GH[base + m], ghz = GH[base + 256 + m], ghn = GH[base + 512 + m];
  float4 hv = h[idx];
  float4 hn;
  hn.x = gate1f(gir.x, ghr.x, giz.x, ghz.x, gin.x, ghn.x, hv.x);
  hn.y = gate1f(gir.y, ghr.y, giz.y, ghz.y, gin.y, ghn.y, hv.y);
  hn.z = gate1f(gir.z, ghr.z, giz.z, ghz.z, gin.z, ghn.z, hv.z);
  hn.w = gate1f(gir.w, ghr.w, giz.w, ghz.w, gin.w, ghn.w, hv.w);
  h[idx] = hn;
  ushort4 hb;
  hb.x = f2bf(hn.x); hb.y = f2bf(hn.y); hb.z = f2bf(hn.z); hb.w = f2bf(hn.w);
  hbf[idx] = hb;
}

// ---------------------------------------------------------------------------
// Output head activation: softmax[0:32], softmax[32:47], sigmoid[47:256]
// ---------------------------------------------------------------------------
__global__ void act_kernel(const float* __restrict__ logits,
                           float* __restrict__ out, u16* __restrict__ xbf, int t)
{
  int b = blockIdx.x;      // 1024
  int d = threadIdx.x;     // 256
  __shared__ float sv[DD];
  float v = logits[(size_t)b * DD + d];
  sv[d] = v;
  __syncthreads();
  float res;
  if (d < CAT1) {
    float m = -1e30f;
    for (int j = 0; j < CAT1; ++j) m = fmaxf(m, sv[j]);
    float s = 0.f;
    for (int j = 0; j < CAT1; ++j) s += expf(sv[j] - m);
    res = expf(v - m) / s;
  } else if (d < CAT2E) {
    float m = -1e30f;
    for (int j = CAT1; j < CAT2E; ++j) m = fmaxf(m, sv[j]);
    float s = 0.f;
    for (int j = CAT1; j < CAT2E; ++j) s += expf(sv[j] - m);
    res = expf(v - m) / s;
  } else {
    res = 1.f / (1.f + expf(-v));
  }
  out[((size_t)b * TT + t) * DD + d] = res;
  xbf[b * DD + d] = f2bf(res);
}

// ---------------------------------------------------------------------------
// Prep: fp32 -> bf16 weight conversion; state init
// ---------------------------------------------------------------------------
__global__ void convert_kernel(const float* __restrict__ src, u16* __restrict__ dst, int n)
{
  int i = blockIdx.x * blockDim.x + threadIdx.x;
  if (i < n) dst[i] = f2bf(src[i]);
}

__global__ void prep_state(const float* __restrict__ embed, const float* __restrict__ dyn,
                           u16* __restrict__ globbf,
                           float* __restrict__ h0, u16* __restrict__ h0bf,
                           float* __restrict__ h1, u16* __restrict__ h1bf,
                           u16* __restrict__ xbf)
{
  int idx = blockIdx.x * blockDim.x + threadIdx.x;  // 1M
  int b = idx >> 10, j = idx & 1023;
  const float* e = embed + (size_t)b * 3072;
  globbf[idx] = f2bf(e[j]);
  float v0 = e[1024 + j]; h0[idx] = v0; h0bf[idx] = f2bf(v0);
  float v1 = e[2048 + j]; h1[idx] = v1; h1bf[idx] = f2bf(v1);
  if (j < DD) {
    xbf[b * DD + j] = f2bf(dyn[(size_t)b * (TT * DD) + j]);  // x0
  }
}

// ---------------------------------------------------------------------------
extern "C" void kernel_launch(void* const* d_in, const int* in_sizes, int n_in,
                              void* d_out, int out_size, void* d_ws, size_t ws_size,
                              hipStream_t stream)
{
  const float* embed = (const float*)d_in[0];
  const float* dyn   = (const float*)d_in[1];
  // d_in[2] = seq_len (256, hardcoded)
  const float* W_ih0 = (const float*)d_in[3];
  const float* W_hh0 = (const float*)d_in[4];
  const float* b_ih0 = (const float*)d_in[5];
  const float* b_hh0 = (const float*)d_in[6];
  const float* W_ih1 = (const float*)d_in[7];
  const float* W_hh1 = (const float*)d_in[8];
  const float* b_ih1 = (const float*)d_in[9];
  const float* b_hh1 = (const float*)d_in[10];
  const float* W_fc  = (const float*)d_in[11];
  const float* b_fc  = (const float*)d_in[12];
  float* out = (float*)d_out;

  // workspace carve (256B aligned)
  char* ws = (char*)d_ws;
  size_t off = 0;
  auto carve = [&](size_t bytes) -> void* {
    void* p = ws + off;
    off += (bytes + 255) & ~(size_t)255;
    return p;
  };
  u16* Wih0b = (u16*)carve((size_t)N3H * 1280 * 2);
  u16* Whh0b = (u16*)carve((size_t)N3H * HH * 2);
  u16* Wih1b = (u16*)carve((size_t)N3H * HH * 2);
  u16* Whh1b = (u16*)carve((size_t)N3H * HH * 2);
  u16* Wfcb  = (u16*)carve((size_t)DD * HH * 2);
  u16* globb = (u16*)carve((size_t)BSB * HH * 2);
  u16* xbf   = (u16*)carve((size_t)BSB * DD * 2);
  float* h0f = (float*)carve((size_t)BSB * HH * 4);
  float* h1f = (float*)carve((size_t)BSB * HH * 4);
  u16* h0b   = (u16*)carve((size_t)BSB * HH * 2);
  u16* h1b   = (u16*)carve((size_t)BSB * HH * 2);
  float* Gglob  = (float*)carve((size_t)BSB * N3H * 4);
  float* GI     = (float*)carve((size_t)BSB * N3H * 4);
  float* GH0f   = (float*)carve((size_t)BSB * N3H * 4);
  float* GH1f   = (float*)carve((size_t)BSB * N3H * 4);
  float* logits = (float*)carve((size_t)BSB * DD * 4);
  (void)ws_size;

  // --- prep: weight conversion + state init ---
  {
    int n;
    n = N3H * 1280; convert_kernel<<<(n + 255) / 256, 256, 0, stream>>>(W_ih0, Wih0b, n);
    n = N3H * HH;   convert_kernel<<<(n + 255) / 256, 256, 0, stream>>>(W_hh0, Whh0b, n);
    n = N3H * HH;   convert_kernel<<<(n + 255) / 256, 256, 0, stream>>>(W_ih1, Wih1b, n);
    n = N3H * HH;   convert_kernel<<<(n + 255) / 256, 256, 0, stream>>>(W_hh1, Whh1b, n);
    n = DD * HH;    convert_kernel<<<(n + 255) / 256, 256, 0, stream>>>(W_fc, Wfcb, n);
  }
  prep_state<<<(BSB * HH) / 256, 256, 0, stream>>>(embed, dyn, globb, h0f, h0b, h1f, h1b, xbf);

  const dim3 G1(N3H / BN, BSB / BM, 1);   // (24, 8)
  const dim3 G2(N3H / BN, BSB / BM, 2);

  // --- prologue ---
  {  // Gglob = glob @ W_ih0[:, :H]^T + b_ih0
    GArg g{globb, HH, HH, Wih0b, 1280, N3H, Gglob, N3H, b_ih0, nullptr};
    gemm_bt3<<<G1, 256, 0, stream>>>(g, g);
  }
  {  // GH0(0) = h0 @ W_hh0^T + b_hh0 ; GH1(0) = h1 @ W_hh1^T + b_hh1
    GArg ga{h0b, HH, HH, Whh0b, HH, N3H, GH0f, N3H, b_hh0, nullptr};
    GArg gb{h1b, HH, HH, Whh1b, HH, N3H, GH1f, N3H, b_hh1, nullptr};
    gemm_bt3<<<G2, 256, 0, stream>>>(ga, gb);
  }
  {  // GI0(0) = x0 @ W_ih0[:, H:]^T + Gglob
    GArg g{xbf, DD, DD, Wih0b + HH, 1280, N3H, GI, N3H, nullptr, Gglob};
    gemm_bt3<<<G1, 256, 0, stream>>>(g, g);
  }

  // --- T sequential steps ---
  // Re-scheduled: GH0(t+1)/GH1(t+1) only need post-gate state of step t, so
  // they ride along with GI1(t) (same A=h0) and head(t) (same A=h1) — the
  // 16-block head GEMM's latency hides under GH1's 384 blocks.
  for (int t = 0; t < TT; ++t) {
    bool last = (t == TT - 1);

    gate_kernel<<<(BSB * HH / 4) / 256, 256, 0, stream>>>(
        (const float4*)GI, (const float4*)GH0f, (float4*)h0f, (ushort4*)h0b);

    {  // z0: GI1(t) = h0n @ W_ih1^T + b_ih1 ; z1: GH0(t+1) = h0n @ W_hh0^T + b_hh0
      GArg gi{h0b, HH, HH, Wih1b, HH, N3H, GI, N3H, b_ih1, nullptr};
      GArg gh{h0b, HH, HH, Whh0b, HH, N3H, GH0f, N3H, b_hh0, nullptr};
      gemm_bt3<<<last ? G1 : G2, 256, 0, stream>>>(gi, gh);
    }

    gate_kernel<<<(BSB * HH / 4) / 256, 256, 0, stream>>>(
        (const float4*)GI, (const float4*)GH1f, (float4*)h1f, (ushort4*)h1b);

    {  // z0: logits = h1n @ W_fc^T + b_fc ; z1: GH1(t+1) = h1n @ W_hh1^T + b_hh1
      GArg gc{h1b, HH, HH, Wfcb, HH, DD, logits, DD, b_fc, nullptr};
      GArg gh{h1b, HH, HH, Whh1b, HH, N3H, GH1f, N3H, b_hh1, nullptr};
      gemm_bt3<<<last ? G1 : G2, 256, 0, stream>>>(gc, gh);
    }

    act_kernel<<<BSB, DD, 0, stream>>>(logits, out, xbf, t);

    if (!last) {  // GI0(t+1) = x(t+1) @ W_ih0[:, H:]^T + Gglob
      GArg g{xbf, DD, DD, Wih0b + HH, 1280, N3H, GI, N3H, nullptr, Gglob};
      gemm_bt3<<<G1, 256, 0, stream>>>(g, g);
    }
  }
}

// Round 2
// 25103.525 us; speedup vs baseline: 1.2416x; 1.0032x over previous
//
#include <hip/hip_runtime.h>

// Problem constants
#define HH    1024
#define DD    256
#define BSB   1024
#define TT    256
#define N3H   3072   // 3*H
#define CAT1  32
#define CAT2E 47

typedef unsigned short u16;
typedef short bf16x8 __attribute__((ext_vector_type(8)));
typedef float f32x4  __attribute__((ext_vector_type(4)));

__device__ __forceinline__ u16 f2bf(float f) {
  // round-to-nearest-even fp32 -> bf16 (finite inputs)
  unsigned int x = __float_as_uint(f);
  unsigned int lsb = (x >> 16) & 1u;
  x += 0x7fffu + lsb;
  return (u16)(x >> 16);
}

// async global->LDS, 16B per lane; LDS dest is wave-uniform base + lane*16
__device__ __forceinline__ void gload_lds16(const u16* src, u16* lds) {
  __builtin_amdgcn_global_load_lds(
      (const __attribute__((address_space(1))) void*)src,
      (__attribute__((address_space(3))) void*)lds, 16, 0, 0);
}

// ---------------------------------------------------------------------------
// GEMM: C[M,N] = A[M,K] @ B[N,K]^T (+bias[col]) (+addend[row,col])
// A,B bf16 (raw u16) row-major; C fp32 with per-arg ldc.
// Block 256 threads = 4 waves; tile 128x128, BK=64.
// 2-deep double-buffered pipeline: raw s_barrier + counted vmcnt(8) so the
// next tile's global_load_lds stay in flight across barriers (T3/T4 pattern;
// regime: 1-1.5 blocks/CU, no TLP to hide the drain).
// Staging: global_load_lds dwordx4, LINEAR LDS [128][64], source pre-swizzled
// by slot^(row&7) so the swizzled ds_read_b128 is bank-conflict-free.
// mfma_f32_16x16x32_bf16 layouts (HW-verified m89/m91):
//   A frag: A[m=lane&15][k=(lane>>4)*8+j];  B frag: W[n=lane&15][k=(lane>>4)*8+j]
//   C/D:    col=lane&15, row=(lane>>4)*4+reg
// act=1 (head): fused output activation — softmax[0:32], softmax[32:47],
// sigmoid[47:256]; both softmax groups live in the waveCol==0 quadrant, so
// 16-lane shfl_xor reduces suffice. Writes out[b,t,:] fp32 + xbf bf16.
// ---------------------------------------------------------------------------
struct GArg {
  const u16* A; int lda; int K;
  const u16* B; int ldb; int N;   // N = valid output cols (early-exit guard)
  float* C; int ldc;
  const float* bias;    // nullable
  const float* addend;  // nullable, stride ldc
  float* out;           // act mode: output tensor base
  u16* xout;            // act mode: bf16 next-x
  int tstep;            // act mode: time index
  int act;              // 1 = head+activation epilogue
};

#define BM 128
#define BN 128
#define BK 64

__global__ __launch_bounds__(256, 2) void gemm_bt4(GArg ga, GArg gb)
{
  GArg g = (blockIdx.z == 0) ? ga : gb;
  const int colBase = blockIdx.x * BN;
  if (colBase >= g.N) return;                 // head blocks beyond N=256 exit
  const int rowBase = blockIdx.y * BM;

  __shared__ __align__(16) u16 As[2][BM * BK];   // 2 x 16 KiB
  __shared__ __align__(16) u16 Bs[2][BN * BK];   // 2 x 16 KiB

  const int tid  = threadIdx.x;
  const int wave = tid >> 6;
  const int lane = tid & 63;
  const int q    = lane >> 4;
  const int l16  = lane & 15;
  const int waveRow = (wave >> 1) * 64;
  const int waveCol = (wave & 1) * 64;

  // staging geometry: lane l writes LDS byte (i*4096 + wave*1024 + l*16)
  // -> row = i*32 + wave*8 + (l>>3), slot = l&7.
  // Pre-swizzle source k-chunk by slot^(row&7) = (l&7)^(l>>3).
  const int  srow = wave * 8 + (lane >> 3);
  const int  sswz = ((lane & 7) ^ (lane >> 3)) << 3;   // k-elem offset (x8)
  const u16* aptr = g.A + (size_t)(rowBase + srow) * g.lda + sswz;
  const u16* bptr = g.B + (size_t)(colBase + srow) * g.ldb + sswz;
  const size_t astep = (size_t)32 * g.lda;
  const size_t bstep = (size_t)32 * g.ldb;
  const int ldoff = wave << 9;   // wave-uniform elem offset in each buffer

  f32x4 acc[4][4];
  #pragma unroll
  for (int i = 0; i < 4; ++i)
    #pragma unroll
    for (int j = 0; j < 4; ++j)
      acc[i][j] = (f32x4){0.f, 0.f, 0.f, 0.f};

  const int nk = g.K >> 6;   // K/64 (>= 4 for all our shapes)

  // prologue: stage tiles 0 and 1 (8 loads each per wave)
  #pragma unroll
  for (int i = 0; i < 4; ++i) {
    gload_lds16(aptr + (size_t)i * astep, &As[0][ldoff + (i << 11)]);
    gload_lds16(bptr + (size_t)i * bstep, &Bs[0][ldoff + (i << 11)]);
  }
  #pragma unroll
  for (int i = 0; i < 4; ++i) {
    gload_lds16(aptr + 64 + (size_t)i * astep, &As[1][ldoff + (i << 11)]);
    gload_lds16(bptr + 64 + (size_t)i * bstep, &Bs[1][ldoff + (i << 11)]);
  }

  for (int k = 0; k < nk; ++k) {
    const int cur = k & 1;
    // wait for tile k's 8 loads (oldest); tile k+1's 8 stay in flight
    if (k < nk - 1) {
      asm volatile("s_waitcnt vmcnt(8)" ::: "memory");
    } else {
      asm volatile("s_waitcnt vmcnt(0)" ::: "memory");
    }
    __builtin_amdgcn_s_barrier();       // all waves' tile-k loads retired
    __builtin_amdgcn_sched_barrier(0);

    #pragma unroll
    for (int ks = 0; ks < 2; ++ks) {
      bf16x8 af[4], bfr[4];
      const int kb = (ks << 2) + q;            // 16B slot of wanted k-chunk
      #pragma unroll
      for (int mi = 0; mi < 4; ++mi) {
        int r = waveRow + mi * 16 + l16;
        af[mi] = *(const bf16x8*)&As[cur][(r << 6) + ((kb ^ (l16 & 7)) << 3)];
      }
      #pragma unroll
      for (int ni = 0; ni < 4; ++ni) {
        int r = waveCol + ni * 16 + l16;
        bfr[ni] = *(const bf16x8*)&Bs[cur][(r << 6) + ((kb ^ (l16 & 7)) << 3)];
      }
      #pragma unroll
      for (int mi = 0; mi < 4; ++mi)
        #pragma unroll
        for (int ni = 0; ni < 4; ++ni)
          acc[mi][ni] = __builtin_amdgcn_mfma_f32_16x16x32_bf16(af[mi], bfr[ni], acc[mi][ni], 0, 0, 0);
    }

    __builtin_amdgcn_sched_barrier(0);
    __builtin_amdgcn_s_barrier();       // all waves done reading buf[cur]
    __builtin_amdgcn_sched_barrier(0);
    if (k + 2 < nk) {                   // refill freed buffer with tile k+2
      const int k2 = (k + 2) << 6;
      #pragma unroll
      for (int i = 0; i < 4; ++i) {
        gload_lds16(aptr + k2 + (size_t)i * astep, &As[cur][ldoff + (i << 11)]);
        gload_lds16(bptr + k2 + (size_t)i * bstep, &Bs[cur][ldoff + (i << 11)]);
      }
    }
  }

  if (g.act) {
    // fused head activation epilogue
    const bool smWave = (colBase + waveCol) == 0;   // cols 0..63 quadrant
    #pragma unroll
    for (int mi = 0; mi < 4; ++mi) {
      #pragma unroll
      for (int r = 0; r < 4; ++r) {
        const int row = rowBase + waveRow + mi * 16 + q * 4 + r;  // batch b
        float v[4];
        #pragma unroll
        for (int ni = 0; ni < 4; ++ni)
          v[ni] = acc[mi][ni][r] + g.bias[colBase + waveCol + ni * 16 + l16];
        float res[4];
        if (smWave) {
          // softmax over cols 0..31: v[0] (col l16), v[1] (col 16+l16)
          float m1 = fmaxf(v[0], v[1]);
          #pragma unroll
          for (int msk = 1; msk < 16; msk <<= 1) m1 = fmaxf(m1, __shfl_xor(m1, msk));
          float e0 = expf(v[0] - m1), e1 = expf(v[1] - m1);
          float s1 = e0 + e1;
          #pragma unroll
          for (int msk = 1; msk < 16; msk <<= 1) s1 += __shfl_xor(s1, msk);
          res[0] = e0 / s1;
          res[1] = e1 / s1;
          // softmax over cols 32..46: v[2] (col 32+l16), l16==15 is sigmoid
          float mv = (l16 < 15) ? v[2] : -1e30f;
          #pragma unroll
          for (int msk = 1; msk < 16; msk <<= 1) mv = fmaxf(mv, __shfl_xor(mv, msk));
          float e2 = expf(v[2] - mv);
          float sv = (l16 < 15) ? e2 : 0.f;
          #pragma unroll
          for (int msk = 1; msk < 16; msk <<= 1) sv += __shfl_xor(sv, msk);
          res[2] = (l16 < 15) ? (e2 / sv) : (1.f / (1.f + expf(-v[2])));
          res[3] = 1.f / (1.f + expf(-v[3]));
        } else {
          #pragma unroll
          for (int ni = 0; ni < 4; ++ni)
            res[ni] = 1.f / (1.f + expf(-v[ni]));
        }
        #pragma unroll
        for (int ni = 0; ni < 4; ++ni) {
          const int col = colBase + waveCol + ni * 16 + l16;
          g.out[((size_t)row * TT + g.tstep) * DD + col] = res[ni];
          g.xout[row * DD + col] = f2bf(res[ni]);
        }
      }
    }
    return;
  }

  #pragma unroll
  for (int mi = 0; mi < 4; ++mi) {
    #pragma unroll
    for (int ni = 0; ni < 4; ++ni) {
      #pragma unroll
      for (int r = 0; r < 4; ++r) {
        int row = rowBase + waveRow + mi * 16 + q * 4 + r;
        int col = colBase + waveCol + ni * 16 + l16;
        float v = acc[mi][ni][r];
        if (g.bias)   v += g.bias[col];
        if (g.addend) v += g.addend[(size_t)row * g.ldc + col];
        g.C[(size_t)row * g.ldc + col] = v;
      }
    }
  }
}

// ---------------------------------------------------------------------------
// GRU gate nonlinearity, float4-vectorized: hn = (1-z)*n + z*h
// ---------------------------------------------------------------------------
__device__ __forceinline__ float gate1f(float gir, float ghr, float giz, float ghz,
                                        float gin, float ghn, float hv) {
  float r = 1.f / (1.f + expf(-(gir + ghr)));
  float z = 1.f / (1.f + expf(-(giz + ghz)));
  float n = tanhf(gin + r * ghn);
  return (1.f - z) * n + z * hv;
}

__global__ void gate_kernel(const float4* __restrict__ GI, const float4* __restrict__ GH,
                            float4* __restrict__ h, ushort4* __restrict__ hbf)
{
  int idx = blockIdx.x * blockDim.x + threadIdx.x;   // BS*H/4 = 256K
  int b = idx >> 8, m = idx & 255;                   // m in float4 units (H/4=256)
  size_t base = (size_t)b * 768;                     // 3H/4
  float4 gir = GI[base + m], giz = GI[base + 256 + m], gin = GI[base + 512 + m];
  float4 ghr = GH[base + m], ghz = GH[base + 256 + m], ghn = GH[base + 512 + m];
  float4 hv = h[idx];
  float4 hn;
  hn.x = gate1f(gir.x, ghr.x, giz.x, ghz.x, gin.x, ghn.x, hv.x);
  hn.y = gate1f(gir.y, ghr.y, giz.y, ghz.y, gin.y, ghn.y, hv.y);
  hn.z = gate1f(gir.z, ghr.z, giz.z, ghz.z, gin.z, ghn.z, hv.z);
  hn.w = gate1f(gir.w, ghr.w, giz.w, ghz.w, gin.w, ghn.w, hv.w);
  h[idx] = hn;
  ushort4 hb;
  hb.x = f2bf(hn.x); hb.y = f2bf(hn.y); hb.z = f2bf(hn.z); hb.w = f2bf(hn.w);
  hbf[idx] = hb;
}

// ---------------------------------------------------------------------------
// Prep: fp32 -> bf16 weight conversion; state init
// ---------------------------------------------------------------------------
__global__ void convert_kernel(const float* __restrict__ src, u16* __restrict__ dst, int n)
{
  int i = blockIdx.x * blockDim.x + threadIdx.x;
  if (i < n) dst[i] = f2bf(src[i]);
}

__global__ void prep_state(const float* __restrict__ embed, const float* __restrict__ dyn,
                           u16* __restrict__ globbf,
                           float* __restrict__ h0, u16* __restrict__ h0bf,
                           float* __restrict__ h1, u16* __restrict__ h1bf,
                           u16* __restrict__ xbf)
{
  int idx = blockIdx.x * blockDim.x + threadIdx.x;  // 1M
  int b = idx >> 10, j = idx & 1023;
  const float* e = embed + (size_t)b * 3072;
  globbf[idx] = f2bf(e[j]);
  float v0 = e[1024 + j]; h0[idx] = v0; h0bf[idx] = f2bf(v0);
  float v1 = e[2048 + j]; h1[idx] = v1; h1bf[idx] = f2bf(v1);
  if (j < DD) {
    xbf[b * DD + j] = f2bf(dyn[(size_t)b * (TT * DD) + j]);  // x0
  }
}

// ---------------------------------------------------------------------------
extern "C" void kernel_launch(void* const* d_in, const int* in_sizes, int n_in,
                              void* d_out, int out_size, void* d_ws, size_t ws_size,
                              hipStream_t stream)
{
  const float* embed = (const float*)d_in[0];
  const float* dyn   = (const float*)d_in[1];
  // d_in[2] = seq_len (256, hardcoded)
  const float* W_ih0 = (const float*)d_in[3];
  const float* W_hh0 = (const float*)d_in[4];
  const float* b_ih0 = (const float*)d_in[5];
  const float* b_hh0 = (const float*)d_in[6];
  const float* W_ih1 = (const float*)d_in[7];
  const float* W_hh1 = (const float*)d_in[8];
  const float* b_ih1 = (const float*)d_in[9];
  const float* b_hh1 = (const float*)d_in[10];
  const float* W_fc  = (const float*)d_in[11];
  const float* b_fc  = (const float*)d_in[12];
  float* out = (float*)d_out;

  // workspace carve (256B aligned)
  char* ws = (char*)d_ws;
  size_t off = 0;
  auto carve = [&](size_t bytes) -> void* {
    void* p = ws + off;
    off += (bytes + 255) & ~(size_t)255;
    return p;
  };
  u16* Wih0b = (u16*)carve((size_t)N3H * 1280 * 2);
  u16* Whh0b = (u16*)carve((size_t)N3H * HH * 2);
  u16* Wih1b = (u16*)carve((size_t)N3H * HH * 2);
  u16* Whh1b = (u16*)carve((size_t)N3H * HH * 2);
  u16* Wfcb  = (u16*)carve((size_t)DD * HH * 2);
  u16* globb = (u16*)carve((size_t)BSB * HH * 2);
  u16* xbf   = (u16*)carve((size_t)BSB * DD * 2);
  float* h0f = (float*)carve((size_t)BSB * HH * 4);
  float* h1f = (float*)carve((size_t)BSB * HH * 4);
  u16* h0b   = (u16*)carve((size_t)BSB * HH * 2);
  u16* h1b   = (u16*)carve((size_t)BSB * HH * 2);
  float* Gglob  = (float*)carve((size_t)BSB * N3H * 4);
  float* GI     = (float*)carve((size_t)BSB * N3H * 4);
  float* GH0f   = (float*)carve((size_t)BSB * N3H * 4);
  float* GH1f   = (float*)carve((size_t)BSB * N3H * 4);
  (void)ws_size;

  // --- prep: weight conversion + state init ---
  {
    int n;
    n = N3H * 1280; convert_kernel<<<(n + 255) / 256, 256, 0, stream>>>(W_ih0, Wih0b, n);
    n = N3H * HH;   convert_kernel<<<(n + 255) / 256, 256, 0, stream>>>(W_hh0, Whh0b, n);
    n = N3H * HH;   convert_kernel<<<(n + 255) / 256, 256, 0, stream>>>(W_ih1, Wih1b, n);
    n = N3H * HH;   convert_kernel<<<(n + 255) / 256, 256, 0, stream>>>(W_hh1, Whh1b, n);
    n = DD * HH;    convert_kernel<<<(n + 255) / 256, 256, 0, stream>>>(W_fc, Wfcb, n);
  }
  prep_state<<<(BSB * HH) / 256, 256, 0, stream>>>(embed, dyn, globb, h0f, h0b, h1f, h1b, xbf);

  const dim3 G1(N3H / BN, BSB / BM, 1);   // (24, 8)
  const dim3 G2(N3H / BN, BSB / BM, 2);

  // --- prologue ---
  {  // Gglob = glob @ W_ih0[:, :H]^T + b_ih0
    GArg g{globb, HH, HH, Wih0b, 1280, N3H, Gglob, N3H, b_ih0, nullptr, nullptr, nullptr, 0, 0};
    gemm_bt4<<<G1, 256, 0, stream>>>(g, g);
  }
  {  // GH0(0) = h0 @ W_hh0^T + b_hh0 ; GH1(0) = h1 @ W_hh1^T + b_hh1
    GArg ga{h0b, HH, HH, Whh0b, HH, N3H, GH0f, N3H, b_hh0, nullptr, nullptr, nullptr, 0, 0};
    GArg gb{h1b, HH, HH, Whh1b, HH, N3H, GH1f, N3H, b_hh1, nullptr, nullptr, nullptr, 0, 0};
    gemm_bt4<<<G2, 256, 0, stream>>>(ga, gb);
  }
  {  // GI0(0) = x0 @ W_ih0[:, H:]^T + Gglob
    GArg g{xbf, DD, DD, Wih0b + HH, 1280, N3H, GI, N3H, nullptr, Gglob, nullptr, nullptr, 0, 0};
    gemm_bt4<<<G1, 256, 0, stream>>>(g, g);
  }

  // --- T sequential steps (5 launches each) ---
  // GH0(t+1)/GH1(t+1) ride along with GI1(t) (same A=h0) and head(t) (same
  // A=h1); head's activation is fused into its epilogue (no act kernel, no
  // logits round-trip).
  for (int t = 0; t < TT; ++t) {
    bool last = (t == TT - 1);

    gate_kernel<<<(BSB * HH / 4) / 256, 256, 0, stream>>>(
        (const float4*)GI, (const float4*)GH0f, (float4*)h0f, (ushort4*)h0b);

    {  // z0: GI1(t) = h0n @ W_ih1^T + b_ih1 ; z1: GH0(t+1) = h0n @ W_hh0^T + b_hh0
      GArg gi{h0b, HH, HH, Wih1b, HH, N3H, GI, N3H, b_ih1, nullptr, nullptr, nullptr, 0, 0};
      GArg gh{h0b, HH, HH, Whh0b, HH, N3H, GH0f, N3H, b_hh0, nullptr, nullptr, nullptr, 0, 0};
      gemm_bt4<<<last ? G1 : G2, 256, 0, stream>>>(gi, gh);
    }

    gate_kernel<<<(BSB * HH / 4) / 256, 256, 0, stream>>>(
        (const float4*)GI, (const float4*)GH1f, (float4*)h1f, (ushort4*)h1b);

    {  // z0: head+act (out[:,t,:], next x) ; z1: GH1(t+1) = h1n @ W_hh1^T + b_hh1
      GArg gc{h1b, HH, HH, Wfcb, HH, DD, nullptr, DD, b_fc, nullptr, out, xbf, t, 1};
      GArg gh{h1b, HH, HH, Whh1b, HH, N3H, GH1f, N3H, b_hh1, nullptr, nullptr, nullptr, 0, 0};
      gemm_bt4<<<last ? G1 : G2, 256, 0, stream>>>(gc, gh);
    }

    if (!last) {  // GI0(t+1) = x(t+1) @ W_ih0[:, H:]^T + Gglob
      GArg g{xbf, DD, DD, Wih0b + HH, 1280, N3H, GI, N3H, nullptr, Gglob, nullptr, nullptr, 0, 0};
      gemm_bt4<<<G1, 256, 0, stream>>>(g, g);
    }
  }
}